// Round 7
// baseline (1056.875 us; speedup 1.0000x reference)
//
#include <hip/hip_runtime.h>
#include <math.h>

// Problem constants
constexpr int cB = 2, cS = 4096, cHID = 1024, cNH = 16, cHD = 64, cNL = 128, cSEG = 32, cD = 1024, cBH = 32;
constexpr float cSCALE = 0.35355339059327373f;   // 1/sqrt(sqrt(64))

typedef _Float16 f16x8 __attribute__((ext_vector_type(8)));
typedef float f32x4 __attribute__((ext_vector_type(4)));

__device__ inline void gload_lds16(const void* g, void* l) {
    __builtin_amdgcn_global_load_lds(
        (const __attribute__((address_space(1))) void*)g,
        (__attribute__((address_space(3))) void*)l, 16, 0, 0);
}

// Device-scope grid barrier: bar[0]=count, bar[1]=generation. 128 blocks <= 256 CUs
// (256 thr, ~9 KB LDS) => always co-resident; safe without cooperative launch.
__device__ inline void gridbar(int* bar) {
    __syncthreads();
    if (threadIdx.x == 0) {
        __threadfence();
        int g = atomicAdd(&bar[1], 0);
        if (atomicAdd(&bar[0], 1) == 4 * cBH - 1) {
            atomicExch(&bar[0], 0);
            __threadfence();
            atomicAdd(&bar[1], 1);
        } else {
            while (atomicAdd(&bar[1], 0) == g) __builtin_amdgcn_s_sleep(2);
        }
    }
    __syncthreads();
    __threadfence();
}

// ---------------------------------------------------------------------------
// cast X fp32 -> fp16
// ---------------------------------------------------------------------------
__global__ __launch_bounds__(256) void cast_x(const float* __restrict__ X, _Float16* __restrict__ Xh)
{
    int i = (blockIdx.x * 256 + threadIdx.x) * 4;
    float4 v = *reinterpret_cast<const float4*>(X + i);
    union { _Float16 h[4]; ushort4 u; } p;
    p.h[0] = (_Float16)v.x; p.h[1] = (_Float16)v.y; p.h[2] = (_Float16)v.z; p.h[3] = (_Float16)v.w;
    *reinterpret_cast<ushort4*>(Xh + i) = p.u;
}

// ---------------------------------------------------------------------------
// transpose+cast W (K x N fp32) -> WT (N x K fp16)
// ---------------------------------------------------------------------------
__global__ __launch_bounds__(256) void wcast_t(
    const float* __restrict__ Wq, const float* __restrict__ Wk,
    const float* __restrict__ Wv, const float* __restrict__ Wo,
    _Float16* __restrict__ WqT, _Float16* __restrict__ WkT,
    _Float16* __restrict__ WvT, _Float16* __restrict__ WoT)
{
    __shared__ float tile[32][33];
    const int wsel = blockIdx.z;
    const float* W = (wsel == 0) ? Wq : (wsel == 1 ? Wk : (wsel == 2 ? Wv : Wo));
    _Float16* WT   = (wsel == 0) ? WqT : (wsel == 1 ? WkT : (wsel == 2 ? WvT : WoT));
    const int n0 = blockIdx.x * 32, k0 = blockIdx.y * 32;
    const int t = threadIdx.x;
    const int r = t >> 3, c = (t & 7) * 4;
    float4 v = *reinterpret_cast<const float4*>(W + (size_t)(k0 + r) * cD + n0 + c);
    tile[r][c] = v.x; tile[r][c + 1] = v.y; tile[r][c + 2] = v.z; tile[r][c + 3] = v.w;
    __syncthreads();
    union { _Float16 h[4]; ushort4 u; } p;
    p.h[0] = (_Float16)tile[c + 0][r]; p.h[1] = (_Float16)tile[c + 1][r];
    p.h[2] = (_Float16)tile[c + 2][r]; p.h[3] = (_Float16)tile[c + 3][r];
    *reinterpret_cast<ushort4*>(WT + (size_t)(n0 + r) * cHID + k0 + c) = p.u;
}

// ---------------------------------------------------------------------------
// Xm[b*128+l][:] = (1/32) sum_j mask*X ; mbar = mean mask  (fp32 landmark input)
// ---------------------------------------------------------------------------
__global__ __launch_bounds__(256) void xm_kernel(
    const float* __restrict__ X, const float* __restrict__ mask,
    float* __restrict__ Xm, float* __restrict__ mbar)
{
    const int bl = blockIdx.x;          // b*128 + l
    const int b = bl >> 7, l = bl & 127;
    const int c = threadIdx.x * 4;
    float4 a = {0.f, 0.f, 0.f, 0.f};
    float msum = 0.f;
    for (int j = 0; j < cSEG; ++j) {
        float m = mask[b * cS + l * cSEG + j];
        float4 x = *reinterpret_cast<const float4*>(X + ((size_t)(b * cS + l * cSEG + j)) * cHID + c);
        a.x += m * x.x; a.y += m * x.y; a.z += m * x.z; a.w += m * x.w;
        msum += m;
    }
    const float inv = 1.0f / cSEG;
    a.x *= inv; a.y *= inv; a.z *= inv; a.w *= inv;
    *reinterpret_cast<float4*>(Xm + (size_t)bl * cHID + c) = a;
    if (threadIdx.x == 0) mbar[bl] = msum * inv;
}

// ---------------------------------------------------------------------------
// f16 MFMA GEMM: QKV. XOR-swizzled LDS (kills 8-way ds_read_b128 conflicts).
// ---------------------------------------------------------------------------
__global__ __launch_bounds__(256) void qkv_gemm_f16(
    const _Float16* __restrict__ Xh, const float* __restrict__ mask,
    const _Float16* __restrict__ WqT, const _Float16* __restrict__ WkT, const _Float16* __restrict__ WvT,
    const float* __restrict__ bq, const float* __restrict__ bk, const float* __restrict__ bv,
    _Float16* __restrict__ Qh, _Float16* __restrict__ Kh, _Float16* __restrict__ Vh)
{
    __shared__ __align__(16) _Float16 As[128 * 32];
    __shared__ __align__(16) _Float16 Bs[128 * 32];
    const int wsel = blockIdx.z;
    const _Float16* WT = (wsel == 0) ? WqT : (wsel == 1 ? WkT : WvT);
    const float* bias  = (wsel == 0) ? bq  : (wsel == 1 ? bk  : bv);
    _Float16* Y        = (wsel == 0) ? Qh  : (wsel == 1 ? Kh  : Vh);
    const int n0 = blockIdx.x * 128, m0 = blockIdx.y * 128;
    const int t = threadIdx.x;
    const int wave = t >> 6, lane = t & 63;
    const int wm = (wave >> 1) * 64, wn = (wave & 1) * 64;
    const int quad = lane >> 4, l15 = lane & 15;
    const int srow = wave * 32 + (lane >> 2);
    // XOR swizzle: LDS chunk (lane&3) of row srow holds global chunk (lane&3)^sw
    const int sw = (lane >> 3) & 3;                  // == (srow>>1)&3
    const int scol = ((lane & 3) ^ sw) * 8;
    const int csw = (l15 >> 1) & 3;                  // fragment-read swizzle

    f32x4 acc[4][4];
#pragma unroll
    for (int i = 0; i < 4; ++i)
#pragma unroll
        for (int j = 0; j < 4; ++j) acc[i][j] = (f32x4){0.f, 0.f, 0.f, 0.f};

    for (int k0 = 0; k0 < cHID; k0 += 32) {
        const _Float16* aSrc = Xh + (size_t)(m0 + srow) * cHID + k0 + scol;
        const _Float16* bSrc = WT + (size_t)(n0 + srow) * cHID + k0 + scol;
        gload_lds16(aSrc,              &As[(wave * 32) * 32]);
        gload_lds16(aSrc + 16 * cHID,  &As[(wave * 32 + 16) * 32]);
        gload_lds16(bSrc,              &Bs[(wave * 32) * 32]);
        gload_lds16(bSrc + 16 * cHID,  &Bs[(wave * 32 + 16) * 32]);
        __syncthreads();
        f16x8 af[4], bf[4];
#pragma unroll
        for (int mt = 0; mt < 4; ++mt)
            af[mt] = *reinterpret_cast<const f16x8*>(&As[(wm + mt * 16 + l15) * 32 + (quad ^ csw) * 8]);
#pragma unroll
        for (int nt = 0; nt < 4; ++nt)
            bf[nt] = *reinterpret_cast<const f16x8*>(&Bs[(wn + nt * 16 + l15) * 32 + (quad ^ csw) * 8]);
#pragma unroll
        for (int mt = 0; mt < 4; ++mt)
#pragma unroll
            for (int nt = 0; nt < 4; ++nt)
                acc[mt][nt] = __builtin_amdgcn_mfma_f32_16x16x32_f16(af[mt], bf[nt], acc[mt][nt], 0, 0, 0);
        __syncthreads();
    }
#pragma unroll
    for (int mt = 0; mt < 4; ++mt) {
#pragma unroll
        for (int r = 0; r < 4; ++r) {
            int R = m0 + wm + mt * 16 + quad * 4 + r;
            int b = R >> 12, s = R & (cS - 1);
            float msc = (wsel < 2) ? mask[b * cS + s] * cSCALE : 1.0f;
#pragma unroll
            for (int nt = 0; nt < 4; ++nt) {
                int Cc = n0 + wn + nt * 16 + l15;
                int h = Cc >> 6, d = Cc & 63;
                float val = (acc[mt][nt][r] + bias[Cc]) * msc;
                Y[((size_t)(b * cNH + h) * cS + s) * cHD + d] = (_Float16)val;
            }
        }
    }
}

// ---------------------------------------------------------------------------
// f16 MFMA GEMM: out = ctxh @ Wo + bo (same swizzle)
// ---------------------------------------------------------------------------
__global__ __launch_bounds__(256) void out_gemm_f16(
    const _Float16* __restrict__ Ah, const _Float16* __restrict__ WT,
    const float* __restrict__ bias, float* __restrict__ Y)
{
    __shared__ __align__(16) _Float16 As[128 * 32];
    __shared__ __align__(16) _Float16 Bs[128 * 32];
    const int n0 = blockIdx.x * 128, m0 = blockIdx.y * 128;
    const int t = threadIdx.x;
    const int wave = t >> 6, lane = t & 63;
    const int wm = (wave >> 1) * 64, wn = (wave & 1) * 64;
    const int quad = lane >> 4, l15 = lane & 15;
    const int srow = wave * 32 + (lane >> 2);
    const int sw = (lane >> 3) & 3;
    const int scol = ((lane & 3) ^ sw) * 8;
    const int csw = (l15 >> 1) & 3;

    f32x4 acc[4][4];
#pragma unroll
    for (int i = 0; i < 4; ++i)
#pragma unroll
        for (int j = 0; j < 4; ++j) acc[i][j] = (f32x4){0.f, 0.f, 0.f, 0.f};

    for (int k0 = 0; k0 < cD; k0 += 32) {
        const _Float16* aSrc = Ah + (size_t)(m0 + srow) * cD + k0 + scol;
        const _Float16* bSrc = WT + (size_t)(n0 + srow) * cD + k0 + scol;
        gload_lds16(aSrc,             &As[(wave * 32) * 32]);
        gload_lds16(aSrc + 16 * cD,   &As[(wave * 32 + 16) * 32]);
        gload_lds16(bSrc,             &Bs[(wave * 32) * 32]);
        gload_lds16(bSrc + 16 * cD,   &Bs[(wave * 32 + 16) * 32]);
        __syncthreads();
        f16x8 af[4], bf[4];
#pragma unroll
        for (int mt = 0; mt < 4; ++mt)
            af[mt] = *reinterpret_cast<const f16x8*>(&As[(wm + mt * 16 + l15) * 32 + (quad ^ csw) * 8]);
#pragma unroll
        for (int nt = 0; nt < 4; ++nt)
            bf[nt] = *reinterpret_cast<const f16x8*>(&Bs[(wn + nt * 16 + l15) * 32 + (quad ^ csw) * 8]);
#pragma unroll
        for (int mt = 0; mt < 4; ++mt)
#pragma unroll
            for (int nt = 0; nt < 4; ++nt)
                acc[mt][nt] = __builtin_amdgcn_mfma_f32_16x16x32_f16(af[mt], bf[nt], acc[mt][nt], 0, 0, 0);
        __syncthreads();
    }
#pragma unroll
    for (int mt = 0; mt < 4; ++mt) {
#pragma unroll
        for (int r = 0; r < 4; ++r) {
            int R = m0 + wm + mt * 16 + quad * 4 + r;
#pragma unroll
            for (int nt = 0; nt < 4; ++nt) {
                int Cc = n0 + wn + nt * 16 + l15;
                Y[(size_t)R * cHID + Cc] = acc[mt][nt][r] + bias[Cc];
            }
        }
    }
}

// ---------------------------------------------------------------------------
// Landmark GEMM (fp32, exact path). Emits f16 Qlh/Klh for MFMA consumers.
// ---------------------------------------------------------------------------
__global__ __launch_bounds__(256) void lgemm(
    const float* __restrict__ Xm, const float* __restrict__ mbar,
    const float* __restrict__ Wq, const float* __restrict__ bq,
    const float* __restrict__ Wk, const float* __restrict__ bk,
    float* __restrict__ Ql, float* __restrict__ Kl,
    _Float16* __restrict__ Qlh, _Float16* __restrict__ Klh)
{
    __shared__ __align__(16) float As[16][68];
    __shared__ __align__(16) float Bs[16][68];
    const int tid = threadIdx.x;
    const int wsel = blockIdx.z;
    const float* W    = wsel ? Wk : Wq;
    const float* bias = wsel ? bk : bq;
    float* Yl         = wsel ? Kl : Ql;
    _Float16* Ylh     = wsel ? Klh : Qlh;
    const int c0 = blockIdx.x * 64, r0 = blockIdx.y * 64;
    const int tx = tid & 15, ty = tid >> 4;
    const int am = tid >> 2, ak = (tid & 3) * 4;
    const int bkk = tid >> 4, bn = (tid & 15) * 4;

    float acc[4][4] = {};
    for (int k0 = 0; k0 < cHID; k0 += 16) {
        float4 a4 = *reinterpret_cast<const float4*>(Xm + (size_t)(r0 + am) * cHID + k0 + ak);
        As[ak + 0][am] = a4.x; As[ak + 1][am] = a4.y; As[ak + 2][am] = a4.z; As[ak + 3][am] = a4.w;
        float4 b4 = *reinterpret_cast<const float4*>(W + (size_t)(k0 + bkk) * cD + c0 + bn);
        *reinterpret_cast<float4*>(&Bs[bkk][bn]) = b4;
        __syncthreads();
#pragma unroll
        for (int kk = 0; kk < 16; ++kk) {
            float4 av  = *reinterpret_cast<const float4*>(&As[kk][ty * 4]);
            float4 bv4 = *reinterpret_cast<const float4*>(&Bs[kk][tx * 4]);
            float a_[4] = {av.x, av.y, av.z, av.w};
            float b_[4] = {bv4.x, bv4.y, bv4.z, bv4.w};
#pragma unroll
            for (int i = 0; i < 4; ++i)
#pragma unroll
                for (int j = 0; j < 4; ++j) acc[i][j] += a_[i] * b_[j];
        }
        __syncthreads();
    }
#pragma unroll
    for (int i = 0; i < 4; ++i) {
        int r = r0 + ty * 4 + i;          // b*128 + l
        int b = r >> 7, l = r & 127;
        float mb = mbar[r];
#pragma unroll
        for (int j = 0; j < 4; ++j) {
            int c = c0 + tx * 4 + j;
            int h = c >> 6, d = c & 63;
            float val = (acc[i][j] + mb * bias[c]) * cSCALE;
            size_t idx = ((size_t)(b * cNH + h) * cNL + l) * cHD + d;
            Yl[idx] = val;
            Ylh[idx] = (_Float16)val;
        }
    }
}

// ---------------------------------------------------------------------------
// k2 softmax (fp32-clean path)
// ---------------------------------------------------------------------------
__global__ __launch_bounds__(128) void k2_softmax(
    const float* __restrict__ Ql, const float* __restrict__ Kl, float* __restrict__ k2)
{
    __shared__ __align__(16) float qrow[64];
    __shared__ float red[128];
    int bh = blockIdx.x >> 7, i = blockIdx.x & 127;
    int j = threadIdx.x;
    if (j < 64) qrow[j] = Ql[(bh * cNL + i) * cHD + j];
    __syncthreads();
    const float4* q4  = reinterpret_cast<const float4*>(qrow);
    const float4* kl4 = reinterpret_cast<const float4*>(Kl + (bh * cNL + j) * cHD);
    float dot = 0.f;
#pragma unroll
    for (int u = 0; u < 16; ++u) {
        float4 a = q4[u], b = kl4[u];
        dot += a.x * b.x + a.y * b.y + a.z * b.z + a.w * b.w;
    }
    red[j] = dot; __syncthreads();
    for (int off = 64; off > 0; off >>= 1) { if (j < off) red[j] = fmaxf(red[j], red[j + off]); __syncthreads(); }
    float m = red[0]; __syncthreads();
    float e = expf(dot - m);
    red[j] = e; __syncthreads();
    for (int off = 64; off > 0; off >>= 1) { if (j < off) red[j] += red[j + off]; __syncthreads(); }
    k2[(bh * cNL + i) * cNL + j] = e / red[0];
}

// ---------------------------------------------------------------------------
// Fused Nystrom inverse chain: colsum-max + V0 + 24 Newton-Schulz matmuls in
// ONE launch. grid (4 tiles, 32 bh) = 128 blocks (always co-resident),
// device-scope atomic grid barrier between phases. Math identical fp32.
// bar[0]=count, bar[1]=gen, bar[3]=cmax (float-as-int, positive).
// ---------------------------------------------------------------------------
__device__ inline void nys_step(
    const float* __restrict__ A, const float* __restrict__ Bm, float* __restrict__ C,
    float cs, float ds, int tile, int bh, int tid,
    float (*As)[68], float (*Bs)[68])
{
    const int c0 = (tile & 1) * 64, r0 = (tile >> 1) * 64;
    const int base = bh * cNL * cNL;
    const int tx = tid & 15, ty = tid >> 4;
    const int am = tid >> 2, ak = (tid & 3) * 4;
    const int bkk = tid >> 4, bn = (tid & 15) * 4;

    float acc[4][4] = {};
    for (int k0 = 0; k0 < cNL; k0 += 16) {
        float4 a4 = *reinterpret_cast<const float4*>(A + base + (r0 + am) * cNL + k0 + ak);
        As[ak + 0][am] = a4.x; As[ak + 1][am] = a4.y; As[ak + 2][am] = a4.z; As[ak + 3][am] = a4.w;
        float4 b4 = *reinterpret_cast<const float4*>(Bm + base + (k0 + bkk) * cNL + c0 + bn);
        *reinterpret_cast<float4*>(&Bs[bkk][bn]) = b4;
        __syncthreads();
#pragma unroll
        for (int kk = 0; kk < 16; ++kk) {
            float4 av  = *reinterpret_cast<const float4*>(&As[kk][ty * 4]);
            float4 bv4 = *reinterpret_cast<const float4*>(&Bs[kk][tx * 4]);
            float a_[4] = {av.x, av.y, av.z, av.w};
            float b_[4] = {bv4.x, bv4.y, bv4.z, bv4.w};
#pragma unroll
            for (int i = 0; i < 4; ++i)
#pragma unroll
                for (int j = 0; j < 4; ++j) acc[i][j] += a_[i] * b_[j];
        }
        __syncthreads();
    }
#pragma unroll
    for (int i = 0; i < 4; ++i) {
        int r = r0 + ty * 4 + i;
#pragma unroll
        for (int j = 0; j < 4; ++j) {
            int c = c0 + tx * 4 + j;
            float av = A[base + r * cNL + c];
            C[base + r * cNL + c] = ds * (cs * av - acc[i][j]);
        }
    }
}

__global__ __launch_bounds__(256) void nys_coop(
    const float* __restrict__ k2, float* __restrict__ Vb0, float* __restrict__ Vb1,
    float* __restrict__ Zb, float* __restrict__ T2b, float* __restrict__ T3b,
    int* __restrict__ bar)
{
    __shared__ __align__(16) float As[16][68];
    __shared__ __align__(16) float Bs[16][68];
    __shared__ float cred[8][33];
    __shared__ float shc;
    const int tile = blockIdx.x, bh = blockIdx.y;
    const int t = threadIdx.x;
    const int base = bh * cNL * cNL;

    // Phase 0: global max of column sums of k2
    {
        int j = t & 31, g = t >> 5;
        float s = 0.f;
        int cbase = base + tile * 32 + j;
        for (int r = 0; r < 16; ++r) s += k2[cbase + (g * 16 + r) * cNL];
        cred[g][j] = s;
        __syncthreads();
        if (t < 32) {
            float tot = 0.f;
#pragma unroll
            for (int g2 = 0; g2 < 8; ++g2) tot += cred[g2][t];
#pragma unroll
            for (int w = 1; w < 32; w <<= 1) tot = fmaxf(tot, __shfl_xor(tot, w, 32));
            if (t == 0) atomicMax(&bar[3], __float_as_int(tot));
        }
    }
    gridbar(bar);

    // Phase 1: V0 = k2^T / cmax  (this block's 64x64 quadrant)
    {
        if (t == 0) shc = __int_as_float(atomicAdd(&bar[3], 0));
        __syncthreads();
        float invc = 1.0f / shc;
        int i0 = (tile >> 1) * 64, j0 = (tile & 1) * 64;
        for (int m = 0; m < 16; ++m) {
            int idx = t + m * 256;
            int ii = idx >> 6, jj = idx & 63;
            Vb0[base + (i0 + ii) * cNL + (j0 + jj)] = k2[base + (j0 + jj) * cNL + (i0 + ii)] * invc;
        }
    }
    gridbar(bar);

    // Phase 2: 6 Newton-Schulz iterations (4 matmuls each)
    float* Vc = Vb0; float* Vn = Vb1;
    for (int it = 0; it < 6; ++it) {
        nys_step(k2, Vc, Zb, 0.f, -1.f, tile, bh, t, As, Bs);   gridbar(bar);
        nys_step(Zb, Zb, T2b, 7.f, 1.f, tile, bh, t, As, Bs);   gridbar(bar);
        nys_step(Zb, T2b, T3b, 15.f, 1.f, tile, bh, t, As, Bs); gridbar(bar);
        nys_step(Vc, T3b, Vn, 13.f, 0.25f, tile, bh, t, As, Bs);
        if (it < 5) gridbar(bar);
        float* tmp = Vc; Vc = Vn; Vn = tmp;
    }
    // V6 lands in Vb0 (6 swaps); kernel-boundary flush makes it visible.
}

// ---------------------------------------------------------------------------
// vtrans: Vh[bh][s][d] f16 -> VTh[bh][d][s] f16 (64x64 LDS tiles)
// ---------------------------------------------------------------------------
__global__ __launch_bounds__(256) void vtrans(const _Float16* __restrict__ Vh, _Float16* __restrict__ VTh)
{
    __shared__ ushort T[64][72];
    const int s0 = blockIdx.x * 64, bh = blockIdx.y;
    const int t = threadIdx.x;
    const _Float16* vb = Vh + ((size_t)bh * cS + s0) * cHD;
#pragma unroll
    for (int i = 0; i < 2; ++i) {
        int idx = t + i * 256;
        int row = idx >> 3, c8 = idx & 7;
        f16x8 v = *reinterpret_cast<const f16x8*>(vb + (size_t)row * cHD + c8 * 8);
#pragma unroll
        for (int j = 0; j < 8; ++j) T[row][c8 * 8 + j] = ((ushort*)&v)[j];
    }
    __syncthreads();
    _Float16* vt = VTh + (size_t)bh * cHD * cS;
#pragma unroll
    for (int i = 0; i < 2; ++i) {
        int idx = t + i * 256;
        int d = idx >> 3, s8 = idx & 7;
        f16x8 o;
#pragma unroll
        for (int j = 0; j < 8; ++j) ((ushort*)&o)[j] = T[s8 * 8 + j][d];
        *reinterpret_cast<f16x8*>(vt + (size_t)d * cS + s0 + s8 * 8) = o;
    }
}

// ---------------------------------------------------------------------------
// k3v_mfma: flash-prefill over landmarks (unchanged from R6)
// ---------------------------------------------------------------------------
__global__ __launch_bounds__(256) void k3v_mfma(
    const _Float16* __restrict__ Qlh, const _Float16* __restrict__ Kh,
    const _Float16* __restrict__ VTh, const float* __restrict__ mask,
    float* __restrict__ Opart, float* __restrict__ mpart, float* __restrict__ spart)
{
    __shared__ __align__(16) _Float16 Ps[128 * 72];
    __shared__ float msk[256];
    const int z = blockIdx.x, bh = blockIdx.y;
    const int b = bh >> 4;
    const int sbase = z * 256;
    const int t = threadIdx.x;
    const int wave = t >> 6, lane = t & 63;
    const int quad = lane >> 4, l15 = lane & 15;

    msk[t] = mask[b * cS + sbase + t];

    f16x8 aq[2][2];
    const _Float16* qlg = Qlh + (size_t)bh * cNL * cHD;
#pragma unroll
    for (int mt = 0; mt < 2; ++mt)
#pragma unroll
        for (int k0 = 0; k0 < 2; ++k0)
            aq[mt][k0] = *reinterpret_cast<const f16x8*>(
                qlg + (size_t)(wave * 32 + mt * 16 + l15) * cHD + k0 * 32 + quad * 8);

    float mrun[2][4], srun[2][4];
    f32x4 accO[2][4];
#pragma unroll
    for (int mt = 0; mt < 2; ++mt)
#pragma unroll
        for (int r = 0; r < 4; ++r) { mrun[mt][r] = -1e30f; srun[mt][r] = 0.f; }
#pragma unroll
    for (int mt = 0; mt < 2; ++mt)
#pragma unroll
        for (int dt = 0; dt < 4; ++dt) accO[mt][dt] = (f32x4){0.f, 0.f, 0.f, 0.f};

    __syncthreads();

    const _Float16* kg = Kh + (size_t)bh * cS * cHD;
    const _Float16* vg = VTh + (size_t)bh * cHD * cS;

    for (int step = 0; step < 4; ++step) {
        const int st = sbase + step * 64;
        f32x4 accS[2][4];
#pragma unroll
        for (int mt = 0; mt < 2; ++mt)
#pragma unroll
            for (int nt = 0; nt < 4; ++nt) accS[mt][nt] = (f32x4){0.f, 0.f, 0.f, 0.f};
#pragma unroll
        for (int k0 = 0; k0 < 2; ++k0)
#pragma unroll
            for (int nt = 0; nt < 4; ++nt) {
                f16x8 bk = *reinterpret_cast<const f16x8*>(
                    kg + (size_t)(st + nt * 16 + l15) * cHD + k0 * 32 + quad * 8);
#pragma unroll
                for (int mt = 0; mt < 2; ++mt)
                    accS[mt][nt] = __builtin_amdgcn_mfma_f32_16x16x32_f16(aq[mt][k0], bk, accS[mt][nt], 0, 0, 0);
            }
#pragma unroll
        for (int nt = 0; nt < 4; ++nt) {
            float pen = 1e9f * (1.0f - msk[step * 64 + nt * 16 + l15]);
#pragma unroll
            for (int mt = 0; mt < 2; ++mt)
#pragma unroll
                for (int r = 0; r < 4; ++r) accS[mt][nt][r] -= pen;
        }
#pragma unroll
        for (int mt = 0; mt < 2; ++mt) {
#pragma unroll
            for (int r = 0; r < 4; ++r) {
                float tmax = fmaxf(fmaxf(accS[mt][0][r], accS[mt][1][r]),
                                   fmaxf(accS[mt][2][r], accS[mt][3][r]));
#pragma unroll
                for (int w = 1; w < 16; w <<= 1) tmax = fmaxf(tmax, __shfl_xor(tmax, w, 16));
                float mnew = fmaxf(mrun[mt][r], tmax);
                float alpha = __expf(mrun[mt][r] - mnew);
                float ts = 0.f;
#pragma unroll
                for (int nt = 0; nt < 4; ++nt) {
                    float e = __expf(accS[mt][nt][r] - mnew);
                    accS[mt][nt][r] = e; ts += e;
                }
#pragma unroll
                for (int w = 1; w < 16; w <<= 1) ts += __shfl_xor(ts, w, 16);
                srun[mt][r] = srun[mt][r] * alpha + ts;
                mrun[mt][r] = mnew;
#pragma unroll
                for (int dt = 0; dt < 4; ++dt) accO[mt][dt][r] *= alpha;
            }
        }
#pragma unroll
        for (int mt = 0; mt < 2; ++mt)
#pragma unroll
            for (int nt = 0; nt < 4; ++nt)
#pragma unroll
                for (int r = 0; r < 4; ++r)
                    Ps[(wave * 32 + mt * 16 + quad * 4 + r) * 72 + nt * 16 + l15] =
                        (_Float16)accS[mt][nt][r];
#pragma unroll
        for (int k0 = 0; k0 < 2; ++k0) {
            f16x8 ap[2];
#pragma unroll
            for (int mt = 0; mt < 2; ++mt)
                ap[mt] = *reinterpret_cast<const f16x8*>(
                    &Ps[(wave * 32 + mt * 16 + l15) * 72 + k0 * 32 + quad * 8]);
#pragma unroll
            for (int dt = 0; dt < 4; ++dt) {
                f16x8 bv = *reinterpret_cast<const f16x8*>(
                    vg + (size_t)(dt * 16 + l15) * cS + st + k0 * 32 + quad * 8);
#pragma unroll
                for (int mt = 0; mt < 2; ++mt)
                    accO[mt][dt] = __builtin_amdgcn_mfma_f32_16x16x32_f16(ap[mt], bv, accO[mt][dt], 0, 0, 0);
            }
        }
    }
    const int rowbase = bh * cNL + wave * 32;
#pragma unroll
    for (int mt = 0; mt < 2; ++mt)
#pragma unroll
        for (int dt = 0; dt < 4; ++dt)
#pragma unroll
            for (int r = 0; r < 4; ++r)
                Opart[(size_t)(z * 4096 + rowbase + mt * 16 + quad * 4 + r) * cHD + dt * 16 + l15] =
                    accO[mt][dt][r];
    if (l15 == 0) {
#pragma unroll
        for (int mt = 0; mt < 2; ++mt)
#pragma unroll
            for (int r = 0; r < 4; ++r) {
                int prow = z * 4096 + rowbase + mt * 16 + quad * 4 + r;
                mpart[prow] = mrun[mt][r];
                spart[prow] = srun[mt][r];
            }
    }
}

// ---------------------------------------------------------------------------
// combine 16 chunk-partials
// ---------------------------------------------------------------------------
__global__ __launch_bounds__(256) void k3v_reduce(
    const float* __restrict__ Opart, const float* __restrict__ mpart,
    const float* __restrict__ spart, float* __restrict__ CV)
{
    const int t = threadIdx.x;
    const int row = blockIdx.x * 4 + (t >> 6);
    const int d = t & 63;
    float mstar = -1e30f;
#pragma unroll
    for (int z = 0; z < 16; ++z) mstar = fmaxf(mstar, mpart[z * 4096 + row]);
    float ssum = 0.f, acc = 0.f;
#pragma unroll
    for (int z = 0; z < 16; ++z) {
        float w = __expf(mpart[z * 4096 + row] - mstar);
        ssum += w * spart[z * 4096 + row];
        acc  += w * Opart[(size_t)(z * 4096 + row) * cHD + d];
    }
    CV[(size_t)row * cHD + d] = acc / ssum;
}

// W2T[bh][d][l] (f16) = (V6[bh] @ CV[bh])^T
__global__ __launch_bounds__(256) void w2_matmul(
    const float* __restrict__ V6, const float* __restrict__ CV, _Float16* __restrict__ W2T)
{
    __shared__ __align__(16) float CVs[128][64];
    const int bh = blockIdx.x, t = threadIdx.x;
    for (int k = 0; k < 32; ++k) { int idx = t + k * 256; CVs[idx >> 6][idx & 63] = CV[bh * 8192 + idx]; }
    __syncthreads();
    const int tx = t & 15, ty = t >> 4;
    float acc[8][4] = {};
    for (int k = 0; k < 128; ++k) {
        float4 b4 = *reinterpret_cast<const float4*>(&CVs[k][tx * 4]);
#pragma unroll
        for (int i = 0; i < 8; ++i) {
            float a = V6[(bh * cNL + ty * 8 + i) * cNL + k];
            acc[i][0] += a * b4.x; acc[i][1] += a * b4.y; acc[i][2] += a * b4.z; acc[i][3] += a * b4.w;
        }
    }
    _Float16* wt = W2T + (size_t)bh * cHD * cNL;
#pragma unroll
    for (int i = 0; i < 8; ++i)
#pragma unroll
        for (int j = 0; j < 4; ++j)
            wt[(size_t)(tx * 4 + j) * cNL + ty * 8 + i] = (_Float16)acc[i][j];
}

// ---------------------------------------------------------------------------
// k1_mfma (unchanged from R5)
// ---------------------------------------------------------------------------
__global__ __launch_bounds__(256) void k1_mfma(
    const _Float16* __restrict__ Qh, const _Float16* __restrict__ Klh,
    const _Float16* __restrict__ W2T, _Float16* __restrict__ ctxh)
{
    __shared__ __align__(16) _Float16 Qs[64 * 72];
    __shared__ __align__(16) _Float16 Ps[64 * 136];
    const int s0 = blockIdx.x * 64, bh = blockIdx.y;
    const int b = bh >> 4, h = bh & 15;
    const int t = threadIdx.x;
    const int wave = t >> 6, lane = t & 63;
    const int quad = lane >> 4, l15 = lane & 15;

    {
        const _Float16* qg = Qh + ((size_t)bh * cS + s0) * cHD;
#pragma unroll
        for (int i = 0; i < 2; ++i) {
            int idx = t + i * 256;
            int row = idx >> 3, c8 = idx & 7;
            *reinterpret_cast<f16x8*>(&Qs[row * 72 + c8 * 8]) =
                *reinterpret_cast<const f16x8*>(qg + (size_t)row * cHD + c8 * 8);
        }
    }
    __syncthreads();

    const _Float16* klg = Klh + (size_t)bh * cNL * cHD;
    f32x4 accS[8];
#pragma unroll
    for (int nt = 0; nt < 8; ++nt) accS[nt] = (f32x4){0.f, 0.f, 0.f, 0.f};
#pragma unroll
    for (int k0 = 0; k0 < 2; ++k0) {
        f16x8 aq = *reinterpret_cast<const f16x8*>(&Qs[(wave * 16 + l15) * 72 + k0 * 32 + quad * 8]);
#pragma unroll
        for (int nt = 0; nt < 8; ++nt) {
            f16x8 bk = *reinterpret_cast<const f16x8*>(klg + (size_t)(nt * 16 + l15) * cHD + k0 * 32 + quad * 8);
            accS[nt] = __builtin_amdgcn_mfma_f32_16x16x32_f16(aq, bk, accS[nt], 0, 0, 0);
        }
    }

    float rmax[4] = {-1e30f, -1e30f, -1e30f, -1e30f};
#pragma unroll
    for (int nt = 0; nt < 8; ++nt)
#pragma unroll
        for (int r = 0; r < 4; ++r) rmax[r] = fmaxf(rmax[r], accS[nt][r]);
#pragma unroll
    for (int r = 0; r < 4; ++r)
#pragma unroll
        for (int w = 1; w < 16; w <<= 1) rmax[r] = fmaxf(rmax[r], __shfl_xor(rmax[r], w, 16));
    float rsum[4] = {0.f, 0.f, 0.f, 0.f};
#pragma unroll
    for (int nt = 0; nt < 8; ++nt)
#pragma unroll
        for (int r = 0; r < 4; ++r) { accS[nt][r] = __expf(accS[nt][r] - rmax[r]); rsum[r] += accS[nt][r]; }
#pragma unroll
    for (int r = 0; r < 4; ++r) {
#pragma unroll
        for (int w = 1; w < 16; w <<= 1) rsum[r] += __shfl_xor(rsum[r], w, 16);
        rsum[r] = 1.0f / rsum[r];
    }
#pragma unroll
    for (int nt = 0; nt < 8; ++nt)
#pragma unroll
        for (int r = 0; r < 4; ++r)
            Ps[(wave * 16 + quad * 4 + r) * 136 + nt * 16 + l15] = (_Float16)(accS[nt][r] * rsum[r]);
    __syncthreads();

    const _Float16* wtg = W2T + (size_t)bh * cHD * cNL;
    f32x4 accO[4];
#pragma unroll
    for (int nt = 0; nt < 4; ++nt) accO[nt] = (f32x4){0.f, 0.f, 0.f, 0.f};
#pragma unroll
    for (int k0 = 0; k0 < 4; ++k0) {
        f16x8 ap = *reinterpret_cast<const f16x8*>(&Ps[(wave * 16 + l15) * 136 + k0 * 32 + quad * 8]);
#pragma unroll
        for (int nt = 0; nt < 4; ++nt) {
            f16x8 bw = *reinterpret_cast<const f16x8*>(wtg + (size_t)(nt * 16 + l15) * cNL + k0 * 32 + quad * 8);
            accO[nt] = __builtin_amdgcn_mfma_f32_16x16x32_f16(ap, bw, accO[nt], 0, 0, 0);
        }
    }
#pragma unroll
    for (int nt = 0; nt < 4; ++nt)
#pragma unroll
        for (int r = 0; r < 4; ++r) {
            int s = s0 + wave * 16 + quad * 4 + r;
            int d = nt * 16 + l15;
            ctxh[((size_t)(b * cS) + s) * cD + h * cHD + d] = (_Float16)accO[nt][r];
        }
}

// ---------------------------------------------------------------------------
extern "C" void kernel_launch(void* const* d_in, const int* in_sizes, int n_in,
                              void* d_out, int out_size, void* d_ws, size_t ws_size,
                              hipStream_t stream)
{
    const float* X    = (const float*)d_in[0];
    const float* mask = (const float*)d_in[1];
    const float* Wq   = (const float*)d_in[2];
    const float* bq   = (const float*)d_in[3];
    const float* Wk   = (const float*)d_in[4];
    const float* bk   = (const float*)d_in[5];
    const float* Wv   = (const float*)d_in[6];
    const float* bv   = (const float*)d_in[7];
    const float* Wo   = (const float*)d_in[8];
    const float* bo   = (const float*)d_in[9];
    float* out = (float*)d_out;

    float* ws = (float*)d_ws;
    size_t off = 0;
    const size_t szQKV = (size_t)cBH * cS * cHD;      // 8388608 floats
    const size_t szL   = (size_t)cBH * cNL * cHD;     // 262144
    const size_t szM   = (size_t)cBH * cNL * cNL;     // 524288
    float* Qr   = ws + off; off += szQKV;             // Qh f16 | Opart f32 (2nd half)
    float* Kr   = ws + off; off += szQKV;             // Kh f16 | ctxh f16 (2nd half)
    float* Vr   = ws + off; off += szQKV;             // Vh f16 | VTh f16 (2nd half)
    _Float16* Xh  = (_Float16*)(ws + off); off += szQKV / 2;
    _Float16* WqT = (_Float16*)(ws + off); off += 524288;
    _Float16* WkT = (_Float16*)(ws + off); off += 524288;
    _Float16* WvT = (_Float16*)(ws + off); off += 524288;
    _Float16* WoT = (_Float16*)(ws + off); off += 524288;
    float* Xm   = ws + off; off += (size_t)cB * cNL * cHID;
    float* mbar = ws + off; off += 256;
    float* Ql  = ws + off; off += szL;
    float* Kl  = ws + off; off += szL;
    float* k2  = ws + off; off += szM;
    float* Vb0 = ws + off; off += szM;
    float* Vb1 = ws + off; off += szM;
    float* Zb  = ws + off; off += szM;
    float* T2b = ws + off; off += szM;
    float* T3b = ws + off; off += szM;
    float* CV  = ws + off; off += szL;
    _Float16* Qlh  = (_Float16*)(ws + off); off += szL / 2;
    _Float16* Klh  = (_Float16*)(ws + off); off += szL / 2;
    _Float16* W2Th = (_Float16*)(ws + off); off += szL / 2;
    int*   ibar = (int*)(ws + off); off += 16;        // [0]=cnt [1]=gen [3]=cmax
    float* mpart = ws + off; off += 65536;
    float* spart = ws + off; off += 65536;

    _Float16* Qh   = (_Float16*)Qr;
    float*    Opart = Qr + szQKV / 2;
    _Float16* Kh   = (_Float16*)Kr;
    _Float16* ctxh = (_Float16*)(Kr + szQKV / 2);
    _Float16* Vh   = (_Float16*)Vr;
    _Float16* VTh  = (_Float16*)(Vr + szQKV / 2);

    hipMemsetAsync(ibar, 0, 16, stream);

    cast_x<<<(int)(szQKV / 1024), 256, 0, stream>>>(X, Xh);
    wcast_t<<<dim3(32, 32, 4), 256, 0, stream>>>(Wq, Wk, Wv, Wo, WqT, WkT, WvT, WoT);
    xm_kernel<<<cB * cNL, 256, 0, stream>>>(X, mask, Xm, mbar);

    qkv_gemm_f16<<<dim3(cD / 128, (cB * cS) / 128, 3), 256, 0, stream>>>(
        Xh, mask, WqT, WkT, WvT, bq, bk, bv, Qh, Kh, Vh);
    vtrans<<<dim3(cS / 64, cBH), 256, 0, stream>>>(Vh, VTh);
    lgemm<<<dim3(cD / 64, (cB * cNL) / 64, 2), 256, 0, stream>>>(Xm, mbar, Wq, bq, Wk, bk, Ql, Kl, Qlh, Klh);

    k2_softmax<<<cBH * cNL, 128, 0, stream>>>(Ql, Kl, k2);
    nys_coop<<<dim3(4, cBH), 256, 0, stream>>>(k2, Vb0, Vb1, Zb, T2b, T3b, ibar);

    k3v_mfma<<<dim3(16, cBH), 256, 0, stream>>>(Qlh, Kh, VTh, mask, Opart, mpart, spart);
    k3v_reduce<<<1024, 256, 0, stream>>>(Opart, mpart, spart, CV);
    w2_matmul<<<cBH, 256, 0, stream>>>(Vb0, CV, W2Th);
    k1_mfma<<<dim3(cS / 64, cBH), 256, 0, stream>>>(Qh, Klh, W2Th, ctxh);
    out_gemm_f16<<<dim3(cHID / 128, (cB * cS) / 128), 256, 0, stream>>>(ctxh, WoT, bo, out);
}

// Round 8
// 920.312 us; speedup vs baseline: 1.1484x; 1.1484x over previous
//
#include <hip/hip_runtime.h>
#include <math.h>

// Problem constants
constexpr int cB = 2, cS = 4096, cHID = 1024, cNH = 16, cHD = 64, cNL = 128, cSEG = 32, cD = 1024, cBH = 32;
constexpr float cSCALE = 0.35355339059327373f;   // 1/sqrt(sqrt(64))

typedef _Float16 f16x8 __attribute__((ext_vector_type(8)));
typedef float f32x4 __attribute__((ext_vector_type(4)));

__device__ inline void gload_lds16(const void* g, void* l) {
    __builtin_amdgcn_global_load_lds(
        (const __attribute__((address_space(1))) void*)g,
        (__attribute__((address_space(3))) void*)l, 16, 0, 0);
}

// Device-scope grid barrier: bar[0]=count, bar[1]=generation. 128 blocks are
// always co-resident (256 thr, 10 KB LDS). KEY FIX vs R7: spin with an
// agent-scope atomic LOAD (concurrent, no ownership) instead of atomicAdd RMW
// (127 spinners serialized the coherence point at ~29 us/barrier).
__device__ inline void gridbar(int* bar) {
    __syncthreads();
    if (threadIdx.x == 0) {
        __threadfence();    // publish this block's phase writes
        int g = __hip_atomic_load(&bar[1], __ATOMIC_RELAXED, __HIP_MEMORY_SCOPE_AGENT);
        int a = __hip_atomic_fetch_add(&bar[0], 1, __ATOMIC_ACQ_REL, __HIP_MEMORY_SCOPE_AGENT);
        if (a == 4 * cBH - 1) {
            __hip_atomic_store(&bar[0], 0, __ATOMIC_RELAXED, __HIP_MEMORY_SCOPE_AGENT);
            __hip_atomic_fetch_add(&bar[1], 1, __ATOMIC_RELEASE, __HIP_MEMORY_SCOPE_AGENT);
        } else {
            while (__hip_atomic_load(&bar[1], __ATOMIC_ACQUIRE, __HIP_MEMORY_SCOPE_AGENT) == g)
                __builtin_amdgcn_s_sleep(4);
        }
    }
    __syncthreads();
}

// ---------------------------------------------------------------------------
// cast X fp32 -> fp16
// ---------------------------------------------------------------------------
__global__ __launch_bounds__(256) void cast_x(const float* __restrict__ X, _Float16* __restrict__ Xh)
{
    int i = (blockIdx.x * 256 + threadIdx.x) * 4;
    float4 v = *reinterpret_cast<const float4*>(X + i);
    union { _Float16 h[4]; ushort4 u; } p;
    p.h[0] = (_Float16)v.x; p.h[1] = (_Float16)v.y; p.h[2] = (_Float16)v.z; p.h[3] = (_Float16)v.w;
    *reinterpret_cast<ushort4*>(Xh + i) = p.u;
}

// ---------------------------------------------------------------------------
// transpose+cast W (K x N fp32) -> WT (N x K fp16)
// ---------------------------------------------------------------------------
__global__ __launch_bounds__(256) void wcast_t(
    const float* __restrict__ Wq, const float* __restrict__ Wk,
    const float* __restrict__ Wv, const float* __restrict__ Wo,
    _Float16* __restrict__ WqT, _Float16* __restrict__ WkT,
    _Float16* __restrict__ WvT, _Float16* __restrict__ WoT)
{
    __shared__ float tile[32][33];
    const int wsel = blockIdx.z;
    const float* W = (wsel == 0) ? Wq : (wsel == 1 ? Wk : (wsel == 2 ? Wv : Wo));
    _Float16* WT   = (wsel == 0) ? WqT : (wsel == 1 ? WkT : (wsel == 2 ? WvT : WoT));
    const int n0 = blockIdx.x * 32, k0 = blockIdx.y * 32;
    const int t = threadIdx.x;
    const int r = t >> 3, c = (t & 7) * 4;
    float4 v = *reinterpret_cast<const float4*>(W + (size_t)(k0 + r) * cD + n0 + c);
    tile[r][c] = v.x; tile[r][c + 1] = v.y; tile[r][c + 2] = v.z; tile[r][c + 3] = v.w;
    __syncthreads();
    union { _Float16 h[4]; ushort4 u; } p;
    p.h[0] = (_Float16)tile[c + 0][r]; p.h[1] = (_Float16)tile[c + 1][r];
    p.h[2] = (_Float16)tile[c + 2][r]; p.h[3] = (_Float16)tile[c + 3][r];
    *reinterpret_cast<ushort4*>(WT + (size_t)(n0 + r) * cHID + k0 + c) = p.u;
}

// ---------------------------------------------------------------------------
// Xm[b*128+l][:] = (1/32) sum_j mask*X ; mbar = mean mask  (fp32 landmark input)
// ---------------------------------------------------------------------------
__global__ __launch_bounds__(256) void xm_kernel(
    const float* __restrict__ X, const float* __restrict__ mask,
    float* __restrict__ Xm, float* __restrict__ mbar)
{
    const int bl = blockIdx.x;          // b*128 + l
    const int b = bl >> 7, l = bl & 127;
    const int c = threadIdx.x * 4;
    float4 a = {0.f, 0.f, 0.f, 0.f};
    float msum = 0.f;
    for (int j = 0; j < cSEG; ++j) {
        float m = mask[b * cS + l * cSEG + j];
        float4 x = *reinterpret_cast<const float4*>(X + ((size_t)(b * cS + l * cSEG + j)) * cHID + c);
        a.x += m * x.x; a.y += m * x.y; a.z += m * x.z; a.w += m * x.w;
        msum += m;
    }
    const float inv = 1.0f / cSEG;
    a.x *= inv; a.y *= inv; a.z *= inv; a.w *= inv;
    *reinterpret_cast<float4*>(Xm + (size_t)bl * cHID + c) = a;
    if (threadIdx.x == 0) mbar[bl] = msum * inv;
}

// ---------------------------------------------------------------------------
// f16 MFMA GEMM: QKV. XOR-swizzled LDS (kills 8-way ds_read_b128 conflicts).
// ---------------------------------------------------------------------------
__global__ __launch_bounds__(256) void qkv_gemm_f16(
    const _Float16* __restrict__ Xh, const float* __restrict__ mask,
    const _Float16* __restrict__ WqT, const _Float16* __restrict__ WkT, const _Float16* __restrict__ WvT,
    const float* __restrict__ bq, const float* __restrict__ bk, const float* __restrict__ bv,
    _Float16* __restrict__ Qh, _Float16* __restrict__ Kh, _Float16* __restrict__ Vh)
{
    __shared__ __align__(16) _Float16 As[128 * 32];
    __shared__ __align__(16) _Float16 Bs[128 * 32];
    const int wsel = blockIdx.z;
    const _Float16* WT = (wsel == 0) ? WqT : (wsel == 1 ? WkT : WvT);
    const float* bias  = (wsel == 0) ? bq  : (wsel == 1 ? bk  : bv);
    _Float16* Y        = (wsel == 0) ? Qh  : (wsel == 1 ? Kh  : Vh);
    const int n0 = blockIdx.x * 128, m0 = blockIdx.y * 128;
    const int t = threadIdx.x;
    const int wave = t >> 6, lane = t & 63;
    const int wm = (wave >> 1) * 64, wn = (wave & 1) * 64;
    const int quad = lane >> 4, l15 = lane & 15;
    const int srow = wave * 32 + (lane >> 2);
    const int sw = (lane >> 3) & 3;
    const int scol = ((lane & 3) ^ sw) * 8;
    const int csw = (l15 >> 1) & 3;

    f32x4 acc[4][4];
#pragma unroll
    for (int i = 0; i < 4; ++i)
#pragma unroll
        for (int j = 0; j < 4; ++j) acc[i][j] = (f32x4){0.f, 0.f, 0.f, 0.f};

    for (int k0 = 0; k0 < cHID; k0 += 32) {
        const _Float16* aSrc = Xh + (size_t)(m0 + srow) * cHID + k0 + scol;
        const _Float16* bSrc = WT + (size_t)(n0 + srow) * cHID + k0 + scol;
        gload_lds16(aSrc,              &As[(wave * 32) * 32]);
        gload_lds16(aSrc + 16 * cHID,  &As[(wave * 32 + 16) * 32]);
        gload_lds16(bSrc,              &Bs[(wave * 32) * 32]);
        gload_lds16(bSrc + 16 * cHID,  &Bs[(wave * 32 + 16) * 32]);
        __syncthreads();
        f16x8 af[4], bf[4];
#pragma unroll
        for (int mt = 0; mt < 4; ++mt)
            af[mt] = *reinterpret_cast<const f16x8*>(&As[(wm + mt * 16 + l15) * 32 + (quad ^ csw) * 8]);
#pragma unroll
        for (int nt = 0; nt < 4; ++nt)
            bf[nt] = *reinterpret_cast<const f16x8*>(&Bs[(wn + nt * 16 + l15) * 32 + (quad ^ csw) * 8]);
#pragma unroll
        for (int mt = 0; mt < 4; ++mt)
#pragma unroll
            for (int nt = 0; nt < 4; ++nt)
                acc[mt][nt] = __builtin_amdgcn_mfma_f32_16x16x32_f16(af[mt], bf[nt], acc[mt][nt], 0, 0, 0);
        __syncthreads();
    }
#pragma unroll
    for (int mt = 0; mt < 4; ++mt) {
#pragma unroll
        for (int r = 0; r < 4; ++r) {
            int R = m0 + wm + mt * 16 + quad * 4 + r;
            int b = R >> 12, s = R & (cS - 1);
            float msc = (wsel < 2) ? mask[b * cS + s] * cSCALE : 1.0f;
#pragma unroll
            for (int nt = 0; nt < 4; ++nt) {
                int Cc = n0 + wn + nt * 16 + l15;
                int h = Cc >> 6, d = Cc & 63;
                float val = (acc[mt][nt][r] + bias[Cc]) * msc;
                Y[((size_t)(b * cNH + h) * cS + s) * cHD + d] = (_Float16)val;
            }
        }
    }
}

// ---------------------------------------------------------------------------
// f16 MFMA GEMM: out = ctxh @ Wo + bo (same swizzle)
// ---------------------------------------------------------------------------
__global__ __launch_bounds__(256) void out_gemm_f16(
    const _Float16* __restrict__ Ah, const _Float16* __restrict__ WT,
    const float* __restrict__ bias, float* __restrict__ Y)
{
    __shared__ __align__(16) _Float16 As[128 * 32];
    __shared__ __align__(16) _Float16 Bs[128 * 32];
    const int n0 = blockIdx.x * 128, m0 = blockIdx.y * 128;
    const int t = threadIdx.x;
    const int wave = t >> 6, lane = t & 63;
    const int wm = (wave >> 1) * 64, wn = (wave & 1) * 64;
    const int quad = lane >> 4, l15 = lane & 15;
    const int srow = wave * 32 + (lane >> 2);
    const int sw = (lane >> 3) & 3;
    const int scol = ((lane & 3) ^ sw) * 8;
    const int csw = (l15 >> 1) & 3;

    f32x4 acc[4][4];
#pragma unroll
    for (int i = 0; i < 4; ++i)
#pragma unroll
        for (int j = 0; j < 4; ++j) acc[i][j] = (f32x4){0.f, 0.f, 0.f, 0.f};

    for (int k0 = 0; k0 < cD; k0 += 32) {
        const _Float16* aSrc = Ah + (size_t)(m0 + srow) * cD + k0 + scol;
        const _Float16* bSrc = WT + (size_t)(n0 + srow) * cD + k0 + scol;
        gload_lds16(aSrc,             &As[(wave * 32) * 32]);
        gload_lds16(aSrc + 16 * cD,   &As[(wave * 32 + 16) * 32]);
        gload_lds16(bSrc,             &Bs[(wave * 32) * 32]);
        gload_lds16(bSrc + 16 * cD,   &Bs[(wave * 32 + 16) * 32]);
        __syncthreads();
        f16x8 af[4], bf[4];
#pragma unroll
        for (int mt = 0; mt < 4; ++mt)
            af[mt] = *reinterpret_cast<const f16x8*>(&As[(wm + mt * 16 + l15) * 32 + (quad ^ csw) * 8]);
#pragma unroll
        for (int nt = 0; nt < 4; ++nt)
            bf[nt] = *reinterpret_cast<const f16x8*>(&Bs[(wn + nt * 16 + l15) * 32 + (quad ^ csw) * 8]);
#pragma unroll
        for (int mt = 0; mt < 4; ++mt)
#pragma unroll
            for (int nt = 0; nt < 4; ++nt)
                acc[mt][nt] = __builtin_amdgcn_mfma_f32_16x16x32_f16(af[mt], bf[nt], acc[mt][nt], 0, 0, 0);
        __syncthreads();
    }
#pragma unroll
    for (int mt = 0; mt < 4; ++mt) {
#pragma unroll
        for (int r = 0; r < 4; ++r) {
            int R = m0 + wm + mt * 16 + quad * 4 + r;
#pragma unroll
            for (int nt = 0; nt < 4; ++nt) {
                int Cc = n0 + wn + nt * 16 + l15;
                Y[(size_t)R * cHID + Cc] = acc[mt][nt][r] + bias[Cc];
            }
        }
    }
}

// ---------------------------------------------------------------------------
// Landmark GEMM (fp32, exact path). Emits f16 Qlh/Klh for MFMA consumers.
// ---------------------------------------------------------------------------
__global__ __launch_bounds__(256) void lgemm(
    const float* __restrict__ Xm, const float* __restrict__ mbar,
    const float* __restrict__ Wq, const float* __restrict__ bq,
    const float* __restrict__ Wk, const float* __restrict__ bk,
    float* __restrict__ Ql, float* __restrict__ Kl,
    _Float16* __restrict__ Qlh, _Float16* __restrict__ Klh)
{
    __shared__ __align__(16) float As[16][68];
    __shared__ __align__(16) float Bs[16][68];
    const int tid = threadIdx.x;
    const int wsel = blockIdx.z;
    const float* W    = wsel ? Wk : Wq;
    const float* bias = wsel ? bk : bq;
    float* Yl         = wsel ? Kl : Ql;
    _Float16* Ylh     = wsel ? Klh : Qlh;
    const int c0 = blockIdx.x * 64, r0 = blockIdx.y * 64;
    const int tx = tid & 15, ty = tid >> 4;
    const int am = tid >> 2, ak = (tid & 3) * 4;
    const int bkk = tid >> 4, bn = (tid & 15) * 4;

    float acc[4][4] = {};
    for (int k0 = 0; k0 < cHID; k0 += 16) {
        float4 a4 = *reinterpret_cast<const float4*>(Xm + (size_t)(r0 + am) * cHID + k0 + ak);
        As[ak + 0][am] = a4.x; As[ak + 1][am] = a4.y; As[ak + 2][am] = a4.z; As[ak + 3][am] = a4.w;
        float4 b4 = *reinterpret_cast<const float4*>(W + (size_t)(k0 + bkk) * cD + c0 + bn);
        *reinterpret_cast<float4*>(&Bs[bkk][bn]) = b4;
        __syncthreads();
#pragma unroll
        for (int kk = 0; kk < 16; ++kk) {
            float4 av  = *reinterpret_cast<const float4*>(&As[kk][ty * 4]);
            float4 bv4 = *reinterpret_cast<const float4*>(&Bs[kk][tx * 4]);
            float a_[4] = {av.x, av.y, av.z, av.w};
            float b_[4] = {bv4.x, bv4.y, bv4.z, bv4.w};
#pragma unroll
            for (int i = 0; i < 4; ++i)
#pragma unroll
                for (int j = 0; j < 4; ++j) acc[i][j] += a_[i] * b_[j];
        }
        __syncthreads();
    }
#pragma unroll
    for (int i = 0; i < 4; ++i) {
        int r = r0 + ty * 4 + i;          // b*128 + l
        int b = r >> 7, l = r & 127;
        float mb = mbar[r];
#pragma unroll
        for (int j = 0; j < 4; ++j) {
            int c = c0 + tx * 4 + j;
            int h = c >> 6, d = c & 63;
            float val = (acc[i][j] + mb * bias[c]) * cSCALE;
            size_t idx = ((size_t)(b * cNH + h) * cNL + l) * cHD + d;
            Yl[idx] = val;
            Ylh[idx] = (_Float16)val;
        }
    }
}

// ---------------------------------------------------------------------------
// k2 softmax (fp32-clean path)
// ---------------------------------------------------------------------------
__global__ __launch_bounds__(128) void k2_softmax(
    const float* __restrict__ Ql, const float* __restrict__ Kl, float* __restrict__ k2)
{
    __shared__ __align__(16) float qrow[64];
    __shared__ float red[128];
    int bh = blockIdx.x >> 7, i = blockIdx.x & 127;
    int j = threadIdx.x;
    if (j < 64) qrow[j] = Ql[(bh * cNL + i) * cHD + j];
    __syncthreads();
    const float4* q4  = reinterpret_cast<const float4*>(qrow);
    const float4* kl4 = reinterpret_cast<const float4*>(Kl + (bh * cNL + j) * cHD);
    float dot = 0.f;
#pragma unroll
    for (int u = 0; u < 16; ++u) {
        float4 a = q4[u], b = kl4[u];
        dot += a.x * b.x + a.y * b.y + a.z * b.z + a.w * b.w;
    }
    red[j] = dot; __syncthreads();
    for (int off = 64; off > 0; off >>= 1) { if (j < off) red[j] = fmaxf(red[j], red[j + off]); __syncthreads(); }
    float m = red[0]; __syncthreads();
    float e = expf(dot - m);
    red[j] = e; __syncthreads();
    for (int off = 64; off > 0; off >>= 1) { if (j < off) red[j] += red[j + off]; __syncthreads(); }
    k2[(bh * cNL + i) * cNL + j] = e / red[0];
}

// ---------------------------------------------------------------------------
// Fused Nystrom inverse chain (one launch, fixed load-spin barrier).
// bar[0]=count, bar[1]=gen, bar[3]=cmax (float-as-int, positive).
// ---------------------------------------------------------------------------
__device__ inline void nys_step(
    const float* __restrict__ A, const float* __restrict__ Bm, float* __restrict__ C,
    float cs, float ds, int tile, int bh, int tid,
    float (*As)[68], float (*Bs)[68])
{
    const int c0 = (tile & 1) * 64, r0 = (tile >> 1) * 64;
    const int base = bh * cNL * cNL;
    const int tx = tid & 15, ty = tid >> 4;
    const int am = tid >> 2, ak = (tid & 3) * 4;
    const int bkk = tid >> 4, bn = (tid & 15) * 4;

    float acc[4][4] = {};
    for (int k0 = 0; k0 < cNL; k0 += 16) {
        float4 a4 = *reinterpret_cast<const float4*>(A + base + (r0 + am) * cNL + k0 + ak);
        As[ak + 0][am] = a4.x; As[ak + 1][am] = a4.y; As[ak + 2][am] = a4.z; As[ak + 3][am] = a4.w;
        float4 b4 = *reinterpret_cast<const float4*>(Bm + base + (k0 + bkk) * cNL + c0 + bn);
        *reinterpret_cast<float4*>(&Bs[bkk][bn]) = b4;
        __syncthreads();
#pragma unroll
        for (int kk = 0; kk < 16; ++kk) {
            float4 av  = *reinterpret_cast<const float4*>(&As[kk][ty * 4]);
            float4 bv4 = *reinterpret_cast<const float4*>(&Bs[kk][tx * 4]);
            float a_[4] = {av.x, av.y, av.z, av.w};
            float b_[4] = {bv4.x, bv4.y, bv4.z, bv4.w};
#pragma unroll
            for (int i = 0; i < 4; ++i)
#pragma unroll
                for (int j = 0; j < 4; ++j) acc[i][j] += a_[i] * b_[j];
        }
        __syncthreads();
    }
#pragma unroll
    for (int i = 0; i < 4; ++i) {
        int r = r0 + ty * 4 + i;
#pragma unroll
        for (int j = 0; j < 4; ++j) {
            int c = c0 + tx * 4 + j;
            float av = A[base + r * cNL + c];
            C[base + r * cNL + c] = ds * (cs * av - acc[i][j]);
        }
    }
}

__global__ __launch_bounds__(256) void nys_coop(
    const float* __restrict__ k2, float* __restrict__ Vb0, float* __restrict__ Vb1,
    float* __restrict__ Zb, float* __restrict__ T2b, float* __restrict__ T3b,
    int* __restrict__ bar)
{
    __shared__ __align__(16) float As[16][68];
    __shared__ __align__(16) float Bs[16][68];
    __shared__ float cred[8][33];
    __shared__ float shc;
    const int tile = blockIdx.x, bh = blockIdx.y;
    const int t = threadIdx.x;
    const int base = bh * cNL * cNL;

    // Phase 0: global max of column sums of k2
    {
        int j = t & 31, g = t >> 5;
        float s = 0.f;
        int cbase = base + tile * 32 + j;
        for (int r = 0; r < 16; ++r) s += k2[cbase + (g * 16 + r) * cNL];
        cred[g][j] = s;
        __syncthreads();
        if (t < 32) {
            float tot = 0.f;
#pragma unroll
            for (int g2 = 0; g2 < 8; ++g2) tot += cred[g2][t];
#pragma unroll
            for (int w = 1; w < 32; w <<= 1) tot = fmaxf(tot, __shfl_xor(tot, w, 32));
            if (t == 0) atomicMax(&bar[3], __float_as_int(tot));
        }
    }
    gridbar(bar);

    // Phase 1: V0 = k2^T / cmax  (this block's 64x64 quadrant)
    {
        if (t == 0) shc = __int_as_float(
            __hip_atomic_load(&bar[3], __ATOMIC_RELAXED, __HIP_MEMORY_SCOPE_AGENT));
        __syncthreads();
        float invc = 1.0f / shc;
        int i0 = (tile >> 1) * 64, j0 = (tile & 1) * 64;
        for (int m = 0; m < 16; ++m) {
            int idx = t + m * 256;
            int ii = idx >> 6, jj = idx & 63;
            Vb0[base + (i0 + ii) * cNL + (j0 + jj)] = k2[base + (j0 + jj) * cNL + (i0 + ii)] * invc;
        }
    }
    gridbar(bar);

    // Phase 2: 6 Newton-Schulz iterations (4 matmuls each)
    float* Vc = Vb0; float* Vn = Vb1;
    for (int it = 0; it < 6; ++it) {
        nys_step(k2, Vc, Zb, 0.f, -1.f, tile, bh, t, As, Bs);   gridbar(bar);
        nys_step(Zb, Zb, T2b, 7.f, 1.f, tile, bh, t, As, Bs);   gridbar(bar);
        nys_step(Zb, T2b, T3b, 15.f, 1.f, tile, bh, t, As, Bs); gridbar(bar);
        nys_step(Vc, T3b, Vn, 13.f, 0.25f, tile, bh, t, As, Bs);
        if (it < 5) gridbar(bar);
        float* tmp = Vc; Vc = Vn; Vn = tmp;
    }
    // V6 lands in Vb0 (6 swaps); kernel-boundary flush makes it visible.
}

// ---------------------------------------------------------------------------
// vtrans: Vh[bh][s][d] f16 -> VTh[bh][d][s] f16 (64x64 LDS tiles)
// ---------------------------------------------------------------------------
__global__ __launch_bounds__(256) void vtrans(const _Float16* __restrict__ Vh, _Float16* __restrict__ VTh)
{
    __shared__ ushort T[64][72];
    const int s0 = blockIdx.x * 64, bh = blockIdx.y;
    const int t = threadIdx.x;
    const _Float16* vb = Vh + ((size_t)bh * cS + s0) * cHD;
#pragma unroll
    for (int i = 0; i < 2; ++i) {
        int idx = t + i * 256;
        int row = idx >> 3, c8 = idx & 7;
        f16x8 v = *reinterpret_cast<const f16x8*>(vb + (size_t)row * cHD + c8 * 8);
#pragma unroll
        for (int j = 0; j < 8; ++j) T[row][c8 * 8 + j] = ((ushort*)&v)[j];
    }
    __syncthreads();
    _Float16* vt = VTh + (size_t)bh * cHD * cS;
#pragma unroll
    for (int i = 0; i < 2; ++i) {
        int idx = t + i * 256;
        int d = idx >> 3, s8 = idx & 7;
        f16x8 o;
#pragma unroll
        for (int j = 0; j < 8; ++j) ((ushort*)&o)[j] = T[s8 * 8 + j][d];
        *reinterpret_cast<f16x8*>(vt + (size_t)d * cS + s0 + s8 * 8) = o;
    }
}

// ---------------------------------------------------------------------------
// k3v_mfma: flash-prefill over landmarks (unchanged from R6)
// ---------------------------------------------------------------------------
__global__ __launch_bounds__(256) void k3v_mfma(
    const _Float16* __restrict__ Qlh, const _Float16* __restrict__ Kh,
    const _Float16* __restrict__ VTh, const float* __restrict__ mask,
    float* __restrict__ Opart, float* __restrict__ mpart, float* __restrict__ spart)
{
    __shared__ __align__(16) _Float16 Ps[128 * 72];
    __shared__ float msk[256];
    const int z = blockIdx.x, bh = blockIdx.y;
    const int b = bh >> 4;
    const int sbase = z * 256;
    const int t = threadIdx.x;
    const int wave = t >> 6, lane = t & 63;
    const int quad = lane >> 4, l15 = lane & 15;

    msk[t] = mask[b * cS + sbase + t];

    f16x8 aq[2][2];
    const _Float16* qlg = Qlh + (size_t)bh * cNL * cHD;
#pragma unroll
    for (int mt = 0; mt < 2; ++mt)
#pragma unroll
        for (int k0 = 0; k0 < 2; ++k0)
            aq[mt][k0] = *reinterpret_cast<const f16x8*>(
                qlg + (size_t)(wave * 32 + mt * 16 + l15) * cHD + k0 * 32 + quad * 8);

    float mrun[2][4], srun[2][4];
    f32x4 accO[2][4];
#pragma unroll
    for (int mt = 0; mt < 2; ++mt)
#pragma unroll
        for (int r = 0; r < 4; ++r) { mrun[mt][r] = -1e30f; srun[mt][r] = 0.f; }
#pragma unroll
    for (int mt = 0; mt < 2; ++mt)
#pragma unroll
        for (int dt = 0; dt < 4; ++dt) accO[mt][dt] = (f32x4){0.f, 0.f, 0.f, 0.f};

    __syncthreads();

    const _Float16* kg = Kh + (size_t)bh * cS * cHD;
    const _Float16* vg = VTh + (size_t)bh * cHD * cS;

    for (int step = 0; step < 4; ++step) {
        const int st = sbase + step * 64;
        f32x4 accS[2][4];
#pragma unroll
        for (int mt = 0; mt < 2; ++mt)
#pragma unroll
            for (int nt = 0; nt < 4; ++nt) accS[mt][nt] = (f32x4){0.f, 0.f, 0.f, 0.f};
#pragma unroll
        for (int k0 = 0; k0 < 2; ++k0)
#pragma unroll
            for (int nt = 0; nt < 4; ++nt) {
                f16x8 bk = *reinterpret_cast<const f16x8*>(
                    kg + (size_t)(st + nt * 16 + l15) * cHD + k0 * 32 + quad * 8);
#pragma unroll
                for (int mt = 0; mt < 2; ++mt)
                    accS[mt][nt] = __builtin_amdgcn_mfma_f32_16x16x32_f16(aq[mt][k0], bk, accS[mt][nt], 0, 0, 0);
            }
#pragma unroll
        for (int nt = 0; nt < 4; ++nt) {
            float pen = 1e9f * (1.0f - msk[step * 64 + nt * 16 + l15]);
#pragma unroll
            for (int mt = 0; mt < 2; ++mt)
#pragma unroll
                for (int r = 0; r < 4; ++r) accS[mt][nt][r] -= pen;
        }
#pragma unroll
        for (int mt = 0; mt < 2; ++mt) {
#pragma unroll
            for (int r = 0; r < 4; ++r) {
                float tmax = fmaxf(fmaxf(accS[mt][0][r], accS[mt][1][r]),
                                   fmaxf(accS[mt][2][r], accS[mt][3][r]));
#pragma unroll
                for (int w = 1; w < 16; w <<= 1) tmax = fmaxf(tmax, __shfl_xor(tmax, w, 16));
                float mnew = fmaxf(mrun[mt][r], tmax);
                float alpha = __expf(mrun[mt][r] - mnew);
                float ts = 0.f;
#pragma unroll
                for (int nt = 0; nt < 4; ++nt) {
                    float e = __expf(accS[mt][nt][r] - mnew);
                    accS[mt][nt][r] = e; ts += e;
                }
#pragma unroll
                for (int w = 1; w < 16; w <<= 1) ts += __shfl_xor(ts, w, 16);
                srun[mt][r] = srun[mt][r] * alpha + ts;
                mrun[mt][r] = mnew;
#pragma unroll
                for (int dt = 0; dt < 4; ++dt) accO[mt][dt][r] *= alpha;
            }
        }
#pragma unroll
        for (int mt = 0; mt < 2; ++mt)
#pragma unroll
            for (int nt = 0; nt < 4; ++nt)
#pragma unroll
                for (int r = 0; r < 4; ++r)
                    Ps[(wave * 32 + mt * 16 + quad * 4 + r) * 72 + nt * 16 + l15] =
                        (_Float16)accS[mt][nt][r];
#pragma unroll
        for (int k0 = 0; k0 < 2; ++k0) {
            f16x8 ap[2];
#pragma unroll
            for (int mt = 0; mt < 2; ++mt)
                ap[mt] = *reinterpret_cast<const f16x8*>(
                    &Ps[(wave * 32 + mt * 16 + l15) * 72 + k0 * 32 + quad * 8]);
#pragma unroll
            for (int dt = 0; dt < 4; ++dt) {
                f16x8 bv = *reinterpret_cast<const f16x8*>(
                    vg + (size_t)(dt * 16 + l15) * cS + st + k0 * 32 + quad * 8);
#pragma unroll
                for (int mt = 0; mt < 2; ++mt)
                    accO[mt][dt] = __builtin_amdgcn_mfma_f32_16x16x32_f16(ap[mt], bv, accO[mt][dt], 0, 0, 0);
            }
        }
    }
    const int rowbase = bh * cNL + wave * 32;
#pragma unroll
    for (int mt = 0; mt < 2; ++mt)
#pragma unroll
        for (int dt = 0; dt < 4; ++dt)
#pragma unroll
            for (int r = 0; r < 4; ++r)
                Opart[(size_t)(z * 4096 + rowbase + mt * 16 + quad * 4 + r) * cHD + dt * 16 + l15] =
                    accO[mt][dt][r];
    if (l15 == 0) {
#pragma unroll
        for (int mt = 0; mt < 2; ++mt)
#pragma unroll
            for (int r = 0; r < 4; ++r) {
                int prow = z * 4096 + rowbase + mt * 16 + quad * 4 + r;
                mpart[prow] = mrun[mt][r];
                spart[prow] = srun[mt][r];
            }
    }
}

// ---------------------------------------------------------------------------
// combine 16 chunk-partials
// ---------------------------------------------------------------------------
__global__ __launch_bounds__(256) void k3v_reduce(
    const float* __restrict__ Opart, const float* __restrict__ mpart,
    const float* __restrict__ spart, float* __restrict__ CV)
{
    const int t = threadIdx.x;
    const int row = blockIdx.x * 4 + (t >> 6);
    const int d = t & 63;
    float mstar = -1e30f;
#pragma unroll
    for (int z = 0; z < 16; ++z) mstar = fmaxf(mstar, mpart[z * 4096 + row]);
    float ssum = 0.f, acc = 0.f;
#pragma unroll
    for (int z = 0; z < 16; ++z) {
        float w = __expf(mpart[z * 4096 + row] - mstar);
        ssum += w * spart[z * 4096 + row];
        acc  += w * Opart[(size_t)(z * 4096 + row) * cHD + d];
    }
    CV[(size_t)row * cHD + d] = acc / ssum;
}

// W2T[bh][d][l] (f16) = (V6[bh] @ CV[bh])^T
__global__ __launch_bounds__(256) void w2_matmul(
    const float* __restrict__ V6, const float* __restrict__ CV, _Float16* __restrict__ W2T)
{
    __shared__ __align__(16) float CVs[128][64];
    const int bh = blockIdx.x, t = threadIdx.x;
    for (int k = 0; k < 32; ++k) { int idx = t + k * 256; CVs[idx >> 6][idx & 63] = CV[bh * 8192 + idx]; }
    __syncthreads();
    const int tx = t & 15, ty = t >> 4;
    float acc[8][4] = {};
    for (int k = 0; k < 128; ++k) {
        float4 b4 = *reinterpret_cast<const float4*>(&CVs[k][tx * 4]);
#pragma unroll
        for (int i = 0; i < 8; ++i) {
            float a = V6[(bh * cNL + ty * 8 + i) * cNL + k];
            acc[i][0] += a * b4.x; acc[i][1] += a * b4.y; acc[i][2] += a * b4.z; acc[i][3] += a * b4.w;
        }
    }
    _Float16* wt = W2T + (size_t)bh * cHD * cNL;
#pragma unroll
    for (int i = 0; i < 8; ++i)
#pragma unroll
        for (int j = 0; j < 4; ++j)
            wt[(size_t)(tx * 4 + j) * cNL + ty * 8 + i] = (_Float16)acc[i][j];
}

// ---------------------------------------------------------------------------
// k1_mfma (unchanged from R5)
// ---------------------------------------------------------------------------
__global__ __launch_bounds__(256) void k1_mfma(
    const _Float16* __restrict__ Qh, const _Float16* __restrict__ Klh,
    const _Float16* __restrict__ W2T, _Float16* __restrict__ ctxh)
{
    __shared__ __align__(16) _Float16 Qs[64 * 72];
    __shared__ __align__(16) _Float16 Ps[64 * 136];
    const int s0 = blockIdx.x * 64, bh = blockIdx.y;
    const int b = bh >> 4, h = bh & 15;
    const int t = threadIdx.x;
    const int wave = t >> 6, lane = t & 63;
    const int quad = lane >> 4, l15 = lane & 15;

    {
        const _Float16* qg = Qh + ((size_t)bh * cS + s0) * cHD;
#pragma unroll
        for (int i = 0; i < 2; ++i) {
            int idx = t + i * 256;
            int row = idx >> 3, c8 = idx & 7;
            *reinterpret_cast<f16x8*>(&Qs[row * 72 + c8 * 8]) =
                *reinterpret_cast<const f16x8*>(qg + (size_t)row * cHD + c8 * 8);
        }
    }
    __syncthreads();

    const _Float16* klg = Klh + (size_t)bh * cNL * cHD;
    f32x4 accS[8];
#pragma unroll
    for (int nt = 0; nt < 8; ++nt) accS[nt] = (f32x4){0.f, 0.f, 0.f, 0.f};
#pragma unroll
    for (int k0 = 0; k0 < 2; ++k0) {
        f16x8 aq = *reinterpret_cast<const f16x8*>(&Qs[(wave * 16 + l15) * 72 + k0 * 32 + quad * 8]);
#pragma unroll
        for (int nt = 0; nt < 8; ++nt) {
            f16x8 bk = *reinterpret_cast<const f16x8*>(klg + (size_t)(nt * 16 + l15) * cHD + k0 * 32 + quad * 8);
            accS[nt] = __builtin_amdgcn_mfma_f32_16x16x32_f16(aq, bk, accS[nt], 0, 0, 0);
        }
    }

    float rmax[4] = {-1e30f, -1e30f, -1e30f, -1e30f};
#pragma unroll
    for (int nt = 0; nt < 8; ++nt)
#pragma unroll
        for (int r = 0; r < 4; ++r) rmax[r] = fmaxf(rmax[r], accS[nt][r]);
#pragma unroll
    for (int r = 0; r < 4; ++r)
#pragma unroll
        for (int w = 1; w < 16; w <<= 1) rmax[r] = fmaxf(rmax[r], __shfl_xor(rmax[r], w, 16));
    float rsum[4] = {0.f, 0.f, 0.f, 0.f};
#pragma unroll
    for (int nt = 0; nt < 8; ++nt)
#pragma unroll
        for (int r = 0; r < 4; ++r) { accS[nt][r] = __expf(accS[nt][r] - rmax[r]); rsum[r] += accS[nt][r]; }
#pragma unroll
    for (int r = 0; r < 4; ++r) {
#pragma unroll
        for (int w = 1; w < 16; w <<= 1) rsum[r] += __shfl_xor(rsum[r], w, 16);
        rsum[r] = 1.0f / rsum[r];
    }
#pragma unroll
    for (int nt = 0; nt < 8; ++nt)
#pragma unroll
        for (int r = 0; r < 4; ++r)
            Ps[(wave * 16 + quad * 4 + r) * 136 + nt * 16 + l15] = (_Float16)(accS[nt][r] * rsum[r]);
    __syncthreads();

    const _Float16* wtg = W2T + (size_t)bh * cHD * cNL;
    f32x4 accO[4];
#pragma unroll
    for (int nt = 0; nt < 4; ++nt) accO[nt] = (f32x4){0.f, 0.f, 0.f, 0.f};
#pragma unroll
    for (int k0 = 0; k0 < 4; ++k0) {
        f16x8 ap = *reinterpret_cast<const f16x8*>(&Ps[(wave * 16 + l15) * 136 + k0 * 32 + quad * 8]);
#pragma unroll
        for (int nt = 0; nt < 4; ++nt) {
            f16x8 bw = *reinterpret_cast<const f16x8*>(wtg + (size_t)(nt * 16 + l15) * cNL + k0 * 32 + quad * 8);
            accO[nt] = __builtin_amdgcn_mfma_f32_16x16x32_f16(ap, bw, accO[nt], 0, 0, 0);
        }
    }
#pragma unroll
    for (int nt = 0; nt < 4; ++nt)
#pragma unroll
        for (int r = 0; r < 4; ++r) {
            int s = s0 + wave * 16 + quad * 4 + r;
            int d = nt * 16 + l15;
            ctxh[((size_t)(b * cS) + s) * cD + h * cHD + d] = (_Float16)accO[nt][r];
        }
}

// ---------------------------------------------------------------------------
extern "C" void kernel_launch(void* const* d_in, const int* in_sizes, int n_in,
                              void* d_out, int out_size, void* d_ws, size_t ws_size,
                              hipStream_t stream)
{
    const float* X    = (const float*)d_in[0];
    const float* mask = (const float*)d_in[1];
    const float* Wq   = (const float*)d_in[2];
    const float* bq   = (const float*)d_in[3];
    const float* Wk   = (const float*)d_in[4];
    const float* bk   = (const float*)d_in[5];
    const float* Wv   = (const float*)d_in[6];
    const float* bv   = (const float*)d_in[7];
    const float* Wo   = (const float*)d_in[8];
    const float* bo   = (const float*)d_in[9];
    float* out = (float*)d_out;

    float* ws = (float*)d_ws;
    size_t off = 0;
    const size_t szQKV = (size_t)cBH * cS * cHD;      // 8388608 floats
    const size_t szL   = (size_t)cBH * cNL * cHD;     // 262144
    const size_t szM   = (size_t)cBH * cNL * cNL;     // 524288
    float* Qr   = ws + off; off += szQKV;             // Qh f16 | Opart f32 (2nd half)
    float* Kr   = ws + off; off += szQKV;             // Kh f16 | ctxh f16 (2nd half)
    float* Vr   = ws + off; off += szQKV;             // Vh f16 | VTh f16 (2nd half)
    _Float16* Xh  = (_Float16*)(ws + off); off += szQKV / 2;
    _Float16* WqT = (_Float16*)(ws + off); off += 524288;
    _Float16* WkT = (_Float16*)(ws + off); off += 524288;
    _Float16* WvT = (_Float16*)(ws + off); off += 524288;
    _Float16* WoT = (_Float16*)(ws + off); off += 524288;
    float* Xm   = ws + off; off += (size_t)cB * cNL * cHID;
    float* mbar = ws + off; off += 256;
    float* Ql  = ws + off; off += szL;
    float* Kl  = ws + off; off += szL;
    float* k2  = ws + off; off += szM;
    float* Vb0 = ws + off; off += szM;
    float* Vb1 = ws + off; off += szM;
    float* Zb  = ws + off; off += szM;
    float* T2b = ws + off; off += szM;
    float* T3b = ws + off; off += szM;
    float* CV  = ws + off; off += szL;
    _Float16* Qlh  = (_Float16*)(ws + off); off += szL / 2;
    _Float16* Klh  = (_Float16*)(ws + off); off += szL / 2;
    _Float16* W2Th = (_Float16*)(ws + off); off += szL / 2;
    int*   ibar = (int*)(ws + off); off += 16;        // [0]=cnt [1]=gen [3]=cmax
    float* mpart = ws + off; off += 65536;
    float* spart = ws + off; off += 65536;

    _Float16* Qh   = (_Float16*)Qr;
    float*    Opart = Qr + szQKV / 2;
    _Float16* Kh   = (_Float16*)Kr;
    _Float16* ctxh = (_Float16*)(Kr + szQKV / 2);
    _Float16* Vh   = (_Float16*)Vr;
    _Float16* VTh  = (_Float16*)(Vr + szQKV / 2);

    hipMemsetAsync(ibar, 0, 16, stream);

    cast_x<<<(int)(szQKV / 1024), 256, 0, stream>>>(X, Xh);
    wcast_t<<<dim3(32, 32, 4), 256, 0, stream>>>(Wq, Wk, Wv, Wo, WqT, WkT, WvT, WoT);
    xm_kernel<<<cB * cNL, 256, 0, stream>>>(X, mask, Xm, mbar);

    qkv_gemm_f16<<<dim3(cD / 128, (cB * cS) / 128, 3), 256, 0, stream>>>(
        Xh, mask, WqT, WkT, WvT, bq, bk, bv, Qh, Kh, Vh);
    vtrans<<<dim3(cS / 64, cBH), 256, 0, stream>>>(Vh, VTh);
    lgemm<<<dim3(cD / 64, (cB * cNL) / 64, 2), 256, 0, stream>>>(Xm, mbar, Wq, bq, Wk, bk, Ql, Kl, Qlh, Klh);

    k2_softmax<<<cBH * cNL, 128, 0, stream>>>(Ql, Kl, k2);
    nys_coop<<<dim3(4, cBH), 256, 0, stream>>>(k2, Vb0, Vb1, Zb, T2b, T3b, ibar);

    k3v_mfma<<<dim3(16, cBH), 256, 0, stream>>>(Qlh, Kh, VTh, mask, Opart, mpart, spart);
    k3v_reduce<<<1024, 256, 0, stream>>>(Opart, mpart, spart, CV);
    w2_matmul<<<cBH, 256, 0, stream>>>(Vb0, CV, W2Th);
    k1_mfma<<<dim3(cS / 64, cBH), 256, 0, stream>>>(Qh, Klh, W2Th, ctxh);
    out_gemm_f16<<<dim3(cHID / 128, (cB * cS) / 128), 256, 0, stream>>>(ctxh, WoT, bo, out);
}